// Round 4
// baseline (2760.075 us; speedup 1.0000x reference)
//
#include <hip/hip_runtime.h>
#include <hip/hip_bf16.h>

typedef __hip_bfloat16 bf16;
typedef __bf16 bf16x8 __attribute__((ext_vector_type(8)));
typedef float f32x4 __attribute__((ext_vector_type(4)));

// problem constants
constexpr int NGROUP   = 16;
constexpr int TOK_G    = 100352 / NGROUP;  // 6272 tokens per group (2 images), 49 M-tiles
constexpr int WIN_G    = TOK_G / 49;       // 128 windows per group

// global window-token row -> (b,h,w) flat index (window reverse + roll(+3,+3))
__device__ __forceinline__ long dst_index(int grow) {
  int w  = grow / 49;
  int n  = grow - w * 49;
  int b  = w >> 6;
  int wi = w & 63;
  int wh = wi >> 3, ww = wi & 7;
  int r  = n / 7,  cl = n - (n / 7) * 7;
  int hh = wh * 7 + r + 3;  if (hh >= 56) hh -= 56;
  int vv = ww * 7 + cl + 3; if (vv >= 56) vv -= 56;
  return ((long)b * 3136 + hh * 56 + vv);
}

// ---------------------------------------------------------------------------
// TN GEMM: C[M,N] = A[M,K] (row-major bf16) * Bt[N,K]^T (bf16), fused epilogues.
// 128x128 tile, BK=32, 4 waves, each wave 64x64 via 4x4 MFMA 16x16x32.
// Boring staging: per-thread uint4 global->VGPR->LDS, plain [row][64B] layout.
// EPI: 0 = +bias -> bf16, 1 = +bias + scatter + f32 resid -> f32,
//      2 = +bias + tanh-GELU -> bf16, 3 = +bias + f32 resid -> f32 (in-place ok)
template <int EPI>
__global__ __launch_bounds__(256) void gemm_bt(
    const bf16* __restrict__ A, const bf16* __restrict__ Bt,
    const float* __restrict__ bias, void* __restrict__ Cout_,
    const float* __restrict__ resid, int M, int N, int K, int rowoff) {
  __shared__ __align__(16) char As[128 * 64];  // 128 rows x 32 bf16 (64B/row)
  __shared__ __align__(16) char Bs[128 * 64];

  const int tid  = threadIdx.x;
  const int wv   = tid >> 6;
  const int lane = tid & 63;
  const int quad = lane >> 4;
  const int m0   = blockIdx.y * 128;
  const int n0   = blockIdx.x * 128;
  const int wm   = wv >> 1, wn = wv & 1;
  const int rA0  = wm * 64 + (lane & 15);
  const int rB0  = wn * 64 + (lane & 15);

  const size_t Abytes = (size_t)K * 2;
  const char*  Ab = (const char*)(A  + (size_t)m0 * K);
  const char*  Bb = (const char*)(Bt + (size_t)n0 * K);

  f32x4 acc[4][4];
#pragma unroll
  for (int i = 0; i < 4; ++i)
#pragma unroll
    for (int j = 0; j < 4; ++j) acc[i][j] = (f32x4){0.f, 0.f, 0.f, 0.f};

  for (int k0 = 0; k0 < K; k0 += 32) {
    const size_t kb = (size_t)k0 * 2;   // byte offset of K-slice
#pragma unroll
    for (int i = 0; i < 2; ++i) {
      int c    = i * 256 + tid;         // chunk 0..511
      int srow = c >> 2;
      int kc   = (c & 3) * 16;
      *(uint4*)(As + srow * 64 + kc) =
          *(const uint4*)(Ab + (size_t)srow * Abytes + kb + kc);
      *(uint4*)(Bs + srow * 64 + kc) =
          *(const uint4*)(Bb + (size_t)srow * Abytes + kb + kc);
    }
    __syncthreads();

    bf16x8 af[4], bfr[4];
#pragma unroll
    for (int t = 0; t < 4; ++t) {
      af[t]  = *(const bf16x8*)(As + (rA0 + t * 16) * 64 + quad * 16);
      bfr[t] = *(const bf16x8*)(Bs + (rB0 + t * 16) * 64 + quad * 16);
    }
#pragma unroll
    for (int mt = 0; mt < 4; ++mt)
#pragma unroll
      for (int nt = 0; nt < 4; ++nt)
        acc[mt][nt] = __builtin_amdgcn_mfma_f32_16x16x32_bf16(af[mt], bfr[nt], acc[mt][nt], 0, 0, 0);
    __syncthreads();
  }

  // epilogue  (C/D layout: col = lane&15, row = quad*4 + reg)
  bf16*  CoutB = (bf16*)Cout_;
  float* CoutF = (float*)Cout_;
  float bcol[4];
#pragma unroll
  for (int nt = 0; nt < 4; ++nt)
    bcol[nt] = bias[n0 + wn * 64 + nt * 16 + (lane & 15)];

#pragma unroll
  for (int mt = 0; mt < 4; ++mt) {
#pragma unroll
    for (int r = 0; r < 4; ++r) {
      int grow = m0 + wm * 64 + mt * 16 + quad * 4 + r;
      long dst_row = 0;
      if constexpr (EPI == 1) dst_row = dst_index(rowoff + grow);
#pragma unroll
      for (int nt = 0; nt < 4; ++nt) {
        int col = n0 + wn * 64 + nt * 16 + (lane & 15);
        float v = acc[mt][nt][r] + bcol[nt];
        if constexpr (EPI == 0) {
          CoutB[(size_t)grow * N + col] = __float2bfloat16(v);
        } else if constexpr (EPI == 1) {
          size_t dst = (size_t)dst_row * 384 + col;
          CoutF[dst] = v + resid[dst];
        } else if constexpr (EPI == 2) {
          float u = 0.7978845608f * (v + 0.044715f * v * v * v);
          float t = __expf(2.f * u);
          float g = v * (1.f - 1.f / (t + 1.f));   // 0.5*v*(1+tanh(u))
          CoutB[(size_t)grow * N + col] = __float2bfloat16(g);
        } else {
          size_t dst = (size_t)grow * N + col;
          CoutF[dst] = v + resid[dst];
        }
      }
    }
  }
}

// ---------------------------------------------------------------------------
// LayerNorm, one wave per token; f32 in -> bf16 out.
// gather=1: LN1 + roll(-3,-3) + window partition (rows in window order)
__global__ __launch_bounds__(256) void ln_kernel(
    const float* __restrict__ x, const float* __restrict__ sc,
    const float* __restrict__ bi, bf16* __restrict__ y, int gather, int goff) {
  int tok  = blockIdx.x * 4 + (threadIdx.x >> 6);
  int lane = threadIdx.x & 63;
  size_t src;
  if (gather) {
    int tg = goff + tok;
    int w  = tg / 49, n = tg - (tg / 49) * 49;
    int b  = w >> 6, wi = w & 63;
    int wh = wi >> 3, ww = wi & 7;
    int r  = n / 7, cl = n - (n / 7) * 7;
    int hh = wh * 7 + r + 3;  if (hh >= 56) hh -= 56;
    int vv = ww * 7 + cl + 3; if (vv >= 56) vv -= 56;
    src = ((size_t)b * 3136 + hh * 56 + vv) * 384;
  } else {
    src = (size_t)tok * 384;
  }
  float v[6], s = 0.f, sq = 0.f;
#pragma unroll
  for (int j = 0; j < 6; ++j) {
    v[j] = x[src + lane + j * 64];
    s += v[j]; sq += v[j] * v[j];
  }
#pragma unroll
  for (int m = 32; m; m >>= 1) { s += __shfl_xor(s, m); sq += __shfl_xor(sq, m); }
  float mu  = s * (1.f / 384.f);
  float var = sq * (1.f / 384.f) - mu * mu;
  float rs  = rsqrtf(var + 1e-6f);
#pragma unroll
  for (int j = 0; j < 6; ++j) {
    int c = lane + j * 64;
    y[(size_t)tok * 384 + c] = __float2bfloat16((v[j] - mu) * rs * sc[c] + bi[c]);
  }
}

// ---------------------------------------------------------------------------
// attention: one block per (window, head). N=49, Dh=32. Mask from window coords.
__global__ __launch_bounds__(256) void attn_kernel(
    const bf16* __restrict__ qkv, bf16* __restrict__ O) {
  __shared__ float Qs[1568], Ks[1568], Vs[1568], Ss[49 * 50];
  const int h = blockIdx.x, w = blockIdx.y;  // w group-local; (w&63) == (global&63)
  const int tid = threadIdx.x;
  const int wh  = (w & 63) >> 3, ww = w & 7;
  const size_t base = (size_t)w * 49 * 1152 + h * 32;

  for (int e = tid; e < 1568; e += 256) {
    int n = e >> 5, d = e & 31;
    size_t g = base + (size_t)n * 1152 + d;
    Qs[e] = __bfloat162float(qkv[g]);
    Ks[e] = __bfloat162float(qkv[g + 384]);
    Vs[e] = __bfloat162float(qkv[g + 768]);
  }
  __syncthreads();

  const float scale = 0.17677669529663687f;  // 32^-0.5
  for (int e = tid; e < 2401; e += 256) {
    int n = e / 49, m = e - (e / 49) * 49;
    float dot = 0.f;
#pragma unroll
    for (int d = 0; d < 32; ++d) dot += Qs[n * 32 + d] * Ks[m * 32 + d];
    int rn = n / 7, cn = n - rn * 7, rm = m / 7, cm = m - rm * 7;
    bool sameh = (wh < 7) || ((rn < 4) == (rm < 4));
    bool samew = (ww < 7) || ((cn < 4) == (cm < 4));
    Ss[n * 50 + m] = dot * scale + ((sameh && samew) ? 0.f : -100.f);
  }
  __syncthreads();

  int wv = tid >> 6, lane = tid & 63;
  for (int n = wv; n < 49; n += 4) {
    float sv = (lane < 49) ? Ss[n * 50 + lane] : -1e30f;
    float mx = sv;
#pragma unroll
    for (int m = 32; m; m >>= 1) mx = fmaxf(mx, __shfl_xor(mx, m));
    float p = (lane < 49) ? __expf(sv - mx) : 0.f;
    float sm = p;
#pragma unroll
    for (int m = 32; m; m >>= 1) sm += __shfl_xor(sm, m);
    if (lane < 49) Ss[n * 50 + lane] = p / sm;
  }
  __syncthreads();

  for (int e = tid; e < 1568; e += 256) {
    int n = e >> 5, d = e & 31;
    float o = 0.f;
    for (int m = 0; m < 49; ++m) o += Ss[n * 50 + m] * Vs[m * 32 + d];
    O[((size_t)w * 49 + n) * 384 + h * 32 + d] = __float2bfloat16(o);
  }
}

// ---------------------------------------------------------------------------
// weight transpose: f32 [K][N] row-major -> bf16 [N][K]
__global__ void transpose_bt(const float* __restrict__ in, bf16* __restrict__ out,
                             int K, int N) {
  int idx = blockIdx.x * 256 + threadIdx.x;
  if (idx < K * N) {
    int k = idx / N, n = idx - k * N;
    out[(size_t)n * K + k] = __float2bfloat16(in[idx]);
  }
}

// ---------------------------------------------------------------------------
extern "C" void kernel_launch(void* const* d_in, const int* in_sizes, int n_in,
                              void* d_out, int out_size, void* d_ws, size_t ws_size,
                              hipStream_t stream) {
  const float* x     = (const float*)d_in[0];
  const float* n1s   = (const float*)d_in[1];
  const float* n1b   = (const float*)d_in[2];
  const float* qkvw  = (const float*)d_in[3];
  const float* qkvb  = (const float*)d_in[4];
  const float* projw = (const float*)d_in[5];
  const float* projb = (const float*)d_in[6];
  const float* n2s   = (const float*)d_in[7];
  const float* n2b   = (const float*)d_in[8];
  const float* fc1w  = (const float*)d_in[9];
  const float* fc1b  = (const float*)d_in[10];
  const float* fc2w  = (const float*)d_in[11];
  const float* fc2b  = (const float*)d_in[12];
  float* out = (float*)d_out;   // doubles as the post-attention residual tensor

  // workspace layout (bytes, bf16 buffers); peak ~27.6 MB
  char* ws = (char*)d_ws;
  bf16* yg   = (bf16*)(ws);                   // 4,816,896  LN out (group)
  bf16* Og   = (bf16*)(ws + 4816896);         // 4,816,896  attn out (group)
  bf16* qkvg = (bf16*)(ws + 9633792);         // 14,450,688 qkv (group)
  bf16* hg   = (bf16*)(ws + 4816896);         // 19,267,584 MLP hidden (reuses Og+qkvg)
  bf16* wT0  = (bf16*)(ws + 24084480);        //    884,736 qkv_w^T  [1152,384]
  bf16* wT1  = (bf16*)(ws + 24969216);        //    294,912 proj_w^T [384,384]
  bf16* wT2  = (bf16*)(ws + 25264128);        //  1,179,648 fc1_w^T  [1536,384]
  bf16* wT3  = (bf16*)(ws + 26443776);        //  1,179,648 fc2_w^T  [384,1536]

  transpose_bt<<<(384 * 1152 + 255) / 256, 256, 0, stream>>>(qkvw, wT0, 384, 1152);
  transpose_bt<<<(384 * 384  + 255) / 256, 256, 0, stream>>>(projw, wT1, 384, 384);
  transpose_bt<<<(384 * 1536 + 255) / 256, 256, 0, stream>>>(fc1w, wT2, 384, 1536);
  transpose_bt<<<(1536 * 384 + 255) / 256, 256, 0, stream>>>(fc2w, wT3, 1536, 384);

  // attention half: out <- x + attn(LN1(x))   (scatter epilogue writes f32 d_out)
  for (int g = 0; g < NGROUP; ++g) {
    int roff = g * TOK_G;
    ln_kernel<<<TOK_G / 4, 256, 0, stream>>>(x, n1s, n1b, yg, 1, roff);
    gemm_bt<0><<<dim3(9, TOK_G / 128), 256, 0, stream>>>(
        yg, wT0, qkvb, qkvg, nullptr, TOK_G, 1152, 384, 0);
    attn_kernel<<<dim3(12, WIN_G), 256, 0, stream>>>(qkvg, Og);
    gemm_bt<1><<<dim3(3, TOK_G / 128), 256, 0, stream>>>(
        Og, wT1, projb, out, x, TOK_G, 384, 384, roff);
  }
  // MLP half: out <- out + fc2(gelu(fc1(LN2(out))))   (in-place f32 resid)
  for (int g = 0; g < NGROUP; ++g) {
    long off = (long)g * TOK_G * 384;
    ln_kernel<<<TOK_G / 4, 256, 0, stream>>>(out + off, n2s, n2b, yg, 0, 0);
    gemm_bt<2><<<dim3(12, TOK_G / 128), 256, 0, stream>>>(
        yg, wT2, fc1b, hg, nullptr, TOK_G, 1536, 384, 0);
    gemm_bt<3><<<dim3(3, TOK_G / 128), 256, 0, stream>>>(
        hg, wT3, fc2b, out + off, out + off, TOK_G, 384, 1536, 0);
  }
}